// Round 13
// baseline (67.647 us; speedup 1.0000x reference)
//
#include <hip/hip_runtime.h>
#include <hip/hip_bf16.h>

#define NUM_GT 25
#define NUM_PRED 40
#define PAD 32         // 128 B between global words

// ws u32 word offsets (each on its own 128B line):
//   GT_W(b), b=0..24 : g_gt(b) = sum |gt - b|     (SAD accumulators)
//   PR_W(p), p=0..39 : g_pr(p) = sum |pred - p|
//   OV_W(p), p=0..40 : overlap bitmask row p
#define GT_W(b)  ((b) * PAD)
#define PR_W(p)  ((25 + (p)) * PAD)
#define OV_W(p)  ((65 + (p)) * PAD)
#define WS_WORDS (106 * PAD)

#define GRID  1024
#define BLOCK 256
#define OGRID 2048
#define SGRID 256

#if defined(__has_builtin)
#  if __has_builtin(__builtin_amdgcn_sad_u8)
#    define SAD(A, W, K) (A) = __builtin_amdgcn_sad_u8((W), (K), (A))
#  endif
#endif
#ifndef SAD
#  define SAD(A, W, K) asm("v_sad_u8 %0, %1, %2, %0" : "+v"(A) : "v"(W), "s"(K))
#endif

__device__ __forceinline__ unsigned packg(int4 g) {
    return (unsigned)g.x | ((unsigned)g.y << 8) |
           ((unsigned)g.z << 16) | ((unsigned)g.w << 24);
}
__device__ __forceinline__ unsigned packp(float4 p) {
    return (unsigned)p.x | ((unsigned)p.y << 8) |
           ((unsigned)p.z << 16) | ((unsigned)p.w << 24);
}

// ---------------------------------------------------------------------------
// Seed kernel: populate the GLOBAL overlap table from the first ~524k voxels
// (random data covers all occurring pairs many times over; if it doesn't,
// ovl_kernel still catches everything — this is a pure warm-up optimization).
// ---------------------------------------------------------------------------
__global__ __launch_bounds__(BLOCK) void seed_kernel(
    const float* __restrict__ pred, const int* __restrict__ gt,
    unsigned* __restrict__ ws, int n)
{
    __shared__ unsigned sovl[64];
    const int tid = threadIdx.x;
    if (tid < 64) sovl[tid] = 0u;
    __syncthreads();

    const int n4 = n >> 2;
    const int q = (blockIdx.x * BLOCK + tid) * 2;
    const float4* __restrict__ p4 = (const float4*)pred;
    const int4* __restrict__  g4 = (const int4*)gt;
    if (q + 1 < n4) {
        int4  ga = g4[q], gb = g4[q + 1];
        float4 pa = p4[q], pb = p4[q + 1];
        atomicOr(&sovl[(unsigned)pa.x & 63], 1u << ((unsigned)ga.x & 31));
        atomicOr(&sovl[(unsigned)pa.y & 63], 1u << ((unsigned)ga.y & 31));
        atomicOr(&sovl[(unsigned)pa.z & 63], 1u << ((unsigned)ga.z & 31));
        atomicOr(&sovl[(unsigned)pa.w & 63], 1u << ((unsigned)ga.w & 31));
        atomicOr(&sovl[(unsigned)pb.x & 63], 1u << ((unsigned)gb.x & 31));
        atomicOr(&sovl[(unsigned)pb.y & 63], 1u << ((unsigned)gb.y & 31));
        atomicOr(&sovl[(unsigned)pb.z & 63], 1u << ((unsigned)gb.z & 31));
        atomicOr(&sovl[(unsigned)pb.w & 63], 1u << ((unsigned)gb.w & 31));
    }
    __syncthreads();
    if (tid < 41) {
        unsigned v = sovl[tid];
        if (v) atomicOr(&ws[OV_W(tid)], v);
    }
}

// ---------------------------------------------------------------------------
// Pure SAD kernel: load + byte-pack + 65 v_sad_u8 bins. ZERO LDS operations
// in the hot loop (first time this session) — the decisive ablation of the
// per-voxel LDS-scatter cost that every prior round carried.
// ---------------------------------------------------------------------------
__global__ __launch_bounds__(BLOCK, 3) void sad_kernel(
    const float* __restrict__ pred, const int* __restrict__ gt,
    unsigned* __restrict__ ws, int n)
{
    __shared__ unsigned shist[66];
    __shared__ unsigned stash[4][16][34];

    const int tid  = threadIdx.x;
    const int lane = tid & 63;
    const int wave = tid >> 6;

    if (tid < 66) shist[tid] = 0u;
    __syncthreads();

    unsigned acc[66];
    #pragma unroll
    for (int j = 0; j < 66; ++j) acc[j] = 0u;

    const int gtid   = blockIdx.x * BLOCK + tid;
    const int n16    = n >> 4;
    const int stride = GRID * BLOCK;
    const float4* __restrict__ p4 = (const float4*)pred;
    const int4* __restrict__  g4 = (const int4*)gt;

    for (int i = gtid; i < n16; i += stride) {
        const int q = i * 4;
        int4  ga = g4[q], gb = g4[q + 1], gc = g4[q + 2], gd = g4[q + 3];
        float4 pa = p4[q], pb = p4[q + 1], pc = p4[q + 2], pd = p4[q + 3];

        unsigned GA = packg(ga), GB = packg(gb), GC = packg(gc), GD = packg(gd);
        unsigned PA = packp(pa), PB = packp(pb), PC = packp(pc), PD = packp(pd);

        #pragma unroll
        for (int b = 0; b < 25; ++b) {
            const unsigned K = (unsigned)(b * 0x01010101u);
            SAD(acc[b], GA, K); SAD(acc[b], GB, K);
            SAD(acc[b], GC, K); SAD(acc[b], GD, K);
        }
        #pragma unroll
        for (int b = 0; b < 40; ++b) {
            const unsigned K = (unsigned)(b * 0x01010101u);
            SAD(acc[25 + b], PA, K); SAD(acc[25 + b], PB, K);
            SAD(acc[25 + b], PC, K); SAD(acc[25 + b], PD, K);
        }
    }

    // scalar tail for n % 16 (none for 256^3; defensive)
    if (blockIdx.x == 0 && tid == 0) {
        for (int v = n16 << 4; v < n; ++v) {
            int p = (int)pred[v];
            int g = gt[v];
            for (int b = 0; b < 25; ++b) atomicAdd(&ws[GT_W(b)], (unsigned)abs(g - b));
            for (int b = 0; b < 40; ++b) atomicAdd(&ws[PR_W(b)], (unsigned)abs(p - b));
        }
    }

    // ---- epilogue: pair-packed u16 tree (per-lane acc <= 64 vox * 40 = 2560)
    #pragma unroll
    for (int jp = 0; jp < 33; ++jp) {
        unsigned v = acc[2 * jp] | (acc[2 * jp + 1] << 16);
        v += __shfl_down(v, 32, 64);
        v += __shfl_down(v, 16, 64);
        if (lane < 16) stash[wave][lane][jp] = v;
    }
    __syncthreads();

    for (int i = tid; i < 33 * 16; i += BLOCK) {
        int jp = i >> 4, sl = i & 15;
        unsigned a = stash[0][sl][jp] + stash[1][sl][jp]
                   + stash[2][sl][jp] + stash[3][sl][jp];
        unsigned lo = a & 0xFFFFu, hi = a >> 16;
        lo += __shfl_down(lo, 8, 16);  hi += __shfl_down(hi, 8, 16);
        lo += __shfl_down(lo, 4, 16);  hi += __shfl_down(hi, 4, 16);
        lo += __shfl_down(lo, 2, 16);  hi += __shfl_down(hi, 2, 16);
        lo += __shfl_down(lo, 1, 16);  hi += __shfl_down(hi, 1, 16);
        if (sl == 0) {
            if (lo) atomicAdd(&shist[2 * jp], lo);
            if (hi && 2 * jp + 1 < 65) atomicAdd(&shist[2 * jp + 1], hi);
        }
    }
    __syncthreads();

    for (int i = tid; i < 65; i += BLOCK) {
        unsigned s = shist[i];
        if (s) atomicAdd(&ws[i * PAD], s);
    }
}

// ---------------------------------------------------------------------------
// Overlap kernel: LDS table seeded from the (warm) global table; steady state
// is 16 LDS reads + one AND + a never-taken branch per 16 voxels. Flush only
// if this block discovered a new pair (exact on any data; no-op on random).
// ---------------------------------------------------------------------------
__global__ __launch_bounds__(BLOCK) void ovl_kernel(
    const float* __restrict__ pred, const int* __restrict__ gt,
    unsigned* __restrict__ ws, int n)
{
    __shared__ unsigned sovl[64];
    __shared__ unsigned dirty;
    const int tid = threadIdx.x;

    if (tid < 64) sovl[tid] = (tid < 41) ? ws[OV_W(tid)] : 0u;
    if (tid == 0) dirty = 0u;
    __syncthreads();

    const int n16    = n >> 4;
    const int stride = OGRID * BLOCK;
    const float4* __restrict__ p4 = (const float4*)pred;
    const int4* __restrict__  g4 = (const int4*)gt;

    #define TS(GV, PV)                                                        \
        { unsigned aa = (unsigned)(GV) & 31u, bb = (unsigned)(PV) & 63u;      \
          unsigned m = 1u << aa;                                              \
          if (!(sovl[bb] & m)) atomicOr(&sovl[bb], m); }

    for (int i = blockIdx.x * BLOCK + tid; i < n16; i += stride) {
        const int q = i * 4;
        int4  ga = g4[q], gb = g4[q + 1], gc = g4[q + 2], gd = g4[q + 3];
        float4 pa = p4[q], pb = p4[q + 1], pc = p4[q + 2], pd = p4[q + 3];

        unsigned ok =
              (sovl[(unsigned)pa.x & 63] >> ((unsigned)ga.x & 31))
            & (sovl[(unsigned)pa.y & 63] >> ((unsigned)ga.y & 31))
            & (sovl[(unsigned)pa.z & 63] >> ((unsigned)ga.z & 31))
            & (sovl[(unsigned)pa.w & 63] >> ((unsigned)ga.w & 31))
            & (sovl[(unsigned)pb.x & 63] >> ((unsigned)gb.x & 31))
            & (sovl[(unsigned)pb.y & 63] >> ((unsigned)gb.y & 31))
            & (sovl[(unsigned)pb.z & 63] >> ((unsigned)gb.z & 31))
            & (sovl[(unsigned)pb.w & 63] >> ((unsigned)gb.w & 31))
            & (sovl[(unsigned)pc.x & 63] >> ((unsigned)gc.x & 31))
            & (sovl[(unsigned)pc.y & 63] >> ((unsigned)gc.y & 31))
            & (sovl[(unsigned)pc.z & 63] >> ((unsigned)gc.z & 31))
            & (sovl[(unsigned)pc.w & 63] >> ((unsigned)gc.w & 31))
            & (sovl[(unsigned)pd.x & 63] >> ((unsigned)gd.x & 31))
            & (sovl[(unsigned)pd.y & 63] >> ((unsigned)gd.y & 31))
            & (sovl[(unsigned)pd.z & 63] >> ((unsigned)gd.z & 31))
            & (sovl[(unsigned)pd.w & 63] >> ((unsigned)gd.w & 31));
        if (!(ok & 1u)) {                     // never taken after seeding
            TS(ga.x, pa.x) TS(ga.y, pa.y) TS(ga.z, pa.z) TS(ga.w, pa.w)
            TS(gb.x, pb.x) TS(gb.y, pb.y) TS(gb.z, pb.z) TS(gb.w, pb.w)
            TS(gc.x, pc.x) TS(gc.y, pc.y) TS(gc.z, pc.z) TS(gc.w, pc.w)
            TS(gd.x, pd.x) TS(gd.y, pd.y) TS(gd.z, pd.z) TS(gd.w, pd.w)
            dirty = 1u;
        }
    }
    #undef TS

    // scalar tail for n % 16 (none for 256^3; defensive)
    if (blockIdx.x == 0 && tid == 0) {
        for (int v = n16 << 4; v < n; ++v) {
            int p = (int)pred[v];
            int g = gt[v];
            atomicOr(&ws[OV_W(min(max(p, 0), NUM_PRED))], 1u << (g & 31));
        }
    }

    __syncthreads();
    if (dirty && tid < 41) {
        unsigned v = sovl[tid];
        if (v) atomicOr(&ws[OV_W(tid)], v);
    }
}

// ---------------------------------------------------------------------------
// Finisher: second-difference count extraction (exact int64) + fp64 dice
// (proven absmax = 0, rounds 6-12).
// ---------------------------------------------------------------------------
__global__ __launch_bounds__(64) void finish_kernel(
    const unsigned* __restrict__ ws, float* __restrict__ out, int n)
{
    __shared__ long long gg[25], gp[40], psz[41];
    __shared__ unsigned ov[41];
    const int lane = threadIdx.x;
    if (lane < 25) gg[lane] = (long long)ws[GT_W(lane)];
    if (lane < 40) gp[lane] = (long long)ws[PR_W(lane)];
    if (lane < 41) ov[lane] = ws[OV_W(lane)];
    __syncthreads();

    const long long N = n, Sg = gg[0], Sp = gp[0];

    if (lane < 41) {                         // pred_sizes[P], P = lane
        int P = lane;
        long long f;
        if (P == 0)       f = (N - gp[0] + gp[1]) / 2;
        else if (P <= 38) f = (gp[P - 1] - 2 * gp[P] + gp[P + 1]) / 2;
        else if (P == 39) f = (gp[38] - 2 * gp[39] + (40 * N - Sp)) / 2;
        else              f = (gp[39] - 39 * N + Sp) / 2;   // P = 40
        psz[P] = f;
    }
    __syncthreads();

    double dice = 0.0;
    int present = 0;
    if (lane < 25) {                         // gt component label L = lane+1
        int L = lane + 1;
        long long gs;
        if (L <= 23)      gs = (gg[L - 1] - 2 * gg[L] + gg[L + 1]) / 2;
        else if (L == 24) gs = (gg[23] - 2 * gg[24] + (25 * N - Sg)) / 2;
        else              gs = (gg[24] - 24 * N + Sg) / 2;  // L = 25
        if (gs > 0) {
            present = 1;
            double un = 0.0;
            const unsigned bit = 1u << L;
            for (int p = 0; p < 41; ++p)
                if (ov[p] & bit) un += (double)psz[p];
            dice = 2.0 * (double)gs / (un + (double)gs + 1.0);
        }
    }
    int fp = 0;
    if (lane < 41) {
        if (psz[lane] > 0 && (ov[lane] & 0x3FFFFFEu) == 0) fp = 1;
    }

    int num_gt = __popcll(__ballot(present != 0));
    int nfp    = __popcll(__ballot(fp != 0));
    #pragma unroll
    for (int o = 32; o >= 1; o >>= 1) dice += __shfl_xor(dice, o, 64);

    if (lane == 0) out[0] = (float)(dice / (double)(num_gt + nfp));
}

extern "C" void kernel_launch(void* const* d_in, const int* in_sizes, int n_in,
                              void* d_out, int out_size, void* d_ws, size_t ws_size,
                              hipStream_t stream) {
    const float* pred = (const float*)d_in[0];
    const int* gt = (const int*)d_in[1];
    float* out = (float*)d_out;
    unsigned* ws = (unsigned*)d_ws;
    const int n = in_sizes[0];

    hipMemsetAsync(ws, 0, WS_WORDS * sizeof(unsigned), stream);

    seed_kernel<<<SGRID, BLOCK, 0, stream>>>(pred, gt, ws, n);
    sad_kernel<<<GRID, BLOCK, 0, stream>>>(pred, gt, ws, n);
    ovl_kernel<<<OGRID, BLOCK, 0, stream>>>(pred, gt, ws, n);
    finish_kernel<<<1, 64, 0, stream>>>(ws, out, n);
}